// Round 3
// baseline (265.992 us; speedup 1.0000x reference)
//
#include <hip/hip_runtime.h>
#include <hip/hip_bf16.h>

// ws layout (floats):
//   [128..202]       quantized w_conv (75)
//   [256..44159]     quantized w_fc1 TRANSPOSED [j=343][o=128]
//   [44160..44671]   quantized w_fc2 [4][128]
//   [45056..747519]  pooled features [b=2048][343]
#define WS_WCONV   128
#define WS_W1T     256
#define WS_W2      44160
#define WS_FEAT    45056

__device__ __forceinline__ float q4(float w, float s) {
  if (s <= 0.f) return 0.f;
  float r = rintf(w / s);                     // round-half-even == jnp.round
  r = fminf(fmaxf(r, -8.f), 7.f);
  return r * s;
}

// Single quant dispatch: every fc1 block redundantly computes the global
// max|w1| (172 KB from L2/LLC, ~free) -> no reduce/write dependency pair,
// no serial thread-0 reduction. Block 88 handles conv + fc2 weights.
__global__ __launch_bounds__(256) void quant_all(
    const float* __restrict__ wconv, const float* __restrict__ w1,
    const float* __restrict__ w2, float* __restrict__ ws) {
  __shared__ float red[256];
  int b = blockIdx.x, t = threadIdx.x;
  if (b < 88) {
    const float4* w4 = (const float4*)w1;     // 43904/4 == 10976
    float m = 0.f;
    for (int i = t; i < 10976; i += 256) {
      float4 v = w4[i];
      m = fmaxf(m, fmaxf(fmaxf(fabsf(v.x), fabsf(v.y)),
                         fmaxf(fabsf(v.z), fabsf(v.w))));
    }
    red[t] = m;
    __syncthreads();
    for (int s = 128; s > 0; s >>= 1) {
      if (t < s) red[t] = fmaxf(red[t], red[t + s]);
      __syncthreads();
    }
    float s = red[0] * (1.0f / 7.0f);         // identical in every block
    #pragma unroll
    for (int k = 0; k < 2; ++k) {
      int idx = b * 512 + k * 256 + t;
      if (idx < 43904) {
        float q = q4(w1[idx], s);
        int o = idx / 343;
        int j = idx - o * 343;
        ws[WS_W1T + j * 128 + o] = q;         // transpose for coalesced FC1
      }
    }
  } else {
    float mc = (t < 75) ? fabsf(wconv[t]) : 0.f;
    float m2 = 0.f;
    for (int i = t; i < 512; i += 256) m2 = fmaxf(m2, fabsf(w2[i]));
    red[t] = mc;
    __syncthreads();
    for (int s = 128; s > 0; s >>= 1) {
      if (t < s) red[t] = fmaxf(red[t], red[t + s]);
      __syncthreads();
    }
    float sc = red[0] * (1.0f / 7.0f);
    __syncthreads();
    red[t] = m2;
    __syncthreads();
    for (int s = 128; s > 0; s >>= 1) {
      if (t < s) red[t] = fmaxf(red[t], red[t + s]);
      __syncthreads();
    }
    float s2 = red[0] * (1.0f / 7.0f);
    if (t < 75) ws[WS_WCONV + t] = q4(wconv[t], sc);
    #pragma unroll
    for (int k = 0; k < 2; ++k) {
      int idx = k * 256 + t;
      ws[WS_W2 + idx] = q4(w2[idx], s2);
    }
  }
}

// Conv+pool v3: 2 blocks/batch (depth halves), 37.7 KB LDS -> 4 blocks/CU.
// REGISTER-LEAN inner loop: one row[7] live at a time + c[8] accumulators;
// weights via uniform s_loads. No LDS pad -> staging is a flat float4 copy
// with zero index math. Goal: kill the VGPR=128-cap spill suspected in R2.
__global__ __launch_bounds__(256, 4) void conv_pool(
    const float* __restrict__ x, const float* __restrict__ bconv,
    const float* __restrict__ ws, float* __restrict__ feat) {
  __shared__ float xs[9424];                  // 19 depths * 496 (16*31)
  int t = threadIdx.x;
  int half = blockIdx.x & 1;
  int b = blockIdx.x >> 1;
  int d0 = half ? 16 : 0;                     // staged global depth start
  int nfl4 = half ? 1860 : 2356;              // (15|19)*496/4

  const float4* src = (const float4*)(x + (size_t)b * 15376 + d0 * 496);
  float4* dst = (float4*)xs;
  for (int i = t; i < nfl4; i += 256) dst[i] = src[i];
  __syncthreads();

  int npf = half ? 147 : 196;
  if (t < npf) {
    int pdl = t / 49;                         // local pooled-depth slice
    int rr  = t - pdl * 49;
    int ph  = rr / 7;
    int pw  = rr - ph * 7;
    const float* wq = ws + WS_WCONV;          // uniform idx -> s_load
    float c[2][2][2];                         // [odp][ohp][owp]
    #pragma unroll
    for (int i = 0; i < 8; ++i) ((float*)c)[i] = 0.f;

    int base0 = pdl * (4 * 496) + ph * 62 + pw * 4;
    #pragma unroll
    for (int dd = 0; dd < 7; ++dd) {          // d_local = 4*pdl + dd
      int rbase = base0 + dd * 496;
      #pragma unroll
      for (int hh = 0; hh < 4; ++hh) {        // h = 2*ph + hh
        float row[7];
        #pragma unroll
        for (int wi = 0; wi < 7; ++wi) row[wi] = xs[rbase + hh * 31 + wi];
        #pragma unroll
        for (int odp = 0; odp < 2; ++odp) {
          int kd = dd - 2 * odp;
          if (kd < 0 || kd > 4) continue;     // folds at compile time
          #pragma unroll
          for (int ohp = 0; ohp < 2; ++ohp) {
            int kh = hh - ohp;
            if (kh < 0 || kh > 2) continue;   // folds at compile time
            #pragma unroll
            for (int owp = 0; owp < 2; ++owp) {
              float a = c[odp][ohp][owp];
              #pragma unroll
              for (int kw = 0; kw < 5; ++kw)
                a = fmaf(row[2 * owp + kw], wq[kd * 15 + kh * 5 + kw], a);
              c[odp][ohp][owp] = a;
            }
          }
        }
      }
    }
    float m = ((float*)c)[0];
    #pragma unroll
    for (int i = 1; i < 8; ++i) m = fmaxf(m, ((float*)c)[i]);
    int pd = pdl + (half ? 4 : 0);
    feat[b * 343 + pd * 49 + rr] = m + bconv[0];
  }
}

// FC head: 8 batches/block (256 blocks). w1T element -> 8 FMAs (L2 traffic
// halved vs R2). a1s stride 132 kills the 8-way FC2 bank conflict.
__global__ __launch_bounds__(256) void fc_head(
    const float* __restrict__ ws, const float* __restrict__ bfc1,
    const float* __restrict__ bfc2, float* __restrict__ out) {
  __shared__ float fs[2744];                  // 8 * 343 features, flat
  __shared__ float fc1p[8][128];
  __shared__ float a1s[8][132];               // +4 pad: FC2 reads conflict-free
  __shared__ float s2[32];
  int t = threadIdx.x;
  int b0 = blockIdx.x * 8;

  const float4* fsrc = (const float4*)(ws + WS_FEAT + (size_t)b0 * 343);
  for (int i = t; i < 686; i += 256) ((float4*)fs)[i] = fsrc[i];
  __syncthreads();

  int g = t >> 7, o = t & 127;                // 2 j-halves x 128 outputs
  const float* w1T = ws + WS_W1T;
  float acc[8];
  #pragma unroll
  for (int i = 0; i < 8; ++i) acc[i] = 0.f;
  int j0 = g ? 172 : 0;
  int j1 = g ? 343 : 172;
  for (int j = j0; j < j1; ++j) {
    float w = w1T[j * 128 + o];               // coalesced, 512 B/wave
    #pragma unroll
    for (int bi = 0; bi < 8; ++bi)
      acc[bi] = fmaf(fs[bi * 343 + j], w, acc[bi]);  // LDS broadcast reads
  }
  if (g) {
    #pragma unroll
    for (int bi = 0; bi < 8; ++bi) fc1p[bi][o] = acc[bi];
  }
  __syncthreads();
  if (!g) {
    float bo = bfc1[o];
    #pragma unroll
    for (int bi = 0; bi < 8; ++bi)
      a1s[bi][o] = fmaxf(acc[bi] + fc1p[bi][o] + bo, 0.f);
  }
  __syncthreads();
  if (t < 32) {
    int bb = t >> 2, cls = t & 3;
    const float* w2 = ws + WS_W2 + cls * 128;
    float a = bfc2[cls];
    for (int k = 0; k < 128; ++k) a = fmaf(a1s[bb][k], w2[k], a);
    s2[t] = a;
  }
  __syncthreads();
  if (t < 32) {
    int bb = t >> 2, cls = t & 3;
    float v0 = s2[bb * 4], v1 = s2[bb * 4 + 1];
    float v2 = s2[bb * 4 + 2], v3 = s2[bb * 4 + 3];
    float m = fmaxf(fmaxf(v0, v1), fmaxf(v2, v3));
    float e0 = expf(v0 - m), e1 = expf(v1 - m);
    float e2 = expf(v2 - m), e3 = expf(v3 - m);
    float inv = 1.f / (e0 + e1 + e2 + e3);
    float mine = (cls == 0) ? e0 : (cls == 1) ? e1 : (cls == 2) ? e2 : e3;
    out[(b0 + bb) * 4 + cls] = mine * inv;
  }
}

extern "C" void kernel_launch(void* const* d_in, const int* in_sizes, int n_in,
                              void* d_out, int out_size, void* d_ws, size_t ws_size,
                              hipStream_t stream) {
  const float* x     = (const float*)d_in[0];
  const float* wconv = (const float*)d_in[1];
  const float* bconv = (const float*)d_in[2];
  const float* wfc1  = (const float*)d_in[3];
  const float* bfc1  = (const float*)d_in[4];
  const float* wfc2  = (const float*)d_in[5];
  const float* bfc2  = (const float*)d_in[6];
  float* out = (float*)d_out;
  float* ws  = (float*)d_ws;

  quant_all<<<89, 256, 0, stream>>>(wconv, wfc1, wfc2, ws);
  conv_pool<<<4096, 256, 0, stream>>>(x, bconv, ws, ws + WS_FEAT);
  fc_head<<<256, 256, 0, stream>>>(ws, bfc1, bfc2, out);
}

// Round 4
// 225.679 us; speedup vs baseline: 1.1786x; 1.1786x over previous
//
#include <hip/hip_runtime.h>
#include <hip/hip_bf16.h>

// ws layout (floats):
//   [128..202]       quantized w_conv (75)
//   [256..44159]     quantized w_fc1 TRANSPOSED [j=343][o=128]
//   [44160..44671]   quantized w_fc2 [4][128]
#define WS_WCONV   128
#define WS_W1T     256
#define WS_W2      44160

__device__ __forceinline__ float q4(float w, float s) {
  if (s <= 0.f) return 0.f;
  float r = rintf(w / s);                     // round-half-even == jnp.round
  r = fminf(fmaxf(r, -8.f), 7.f);
  return r * s;
}

// Single quant dispatch (R3-proven, absmax 0): every fc1 block redundantly
// computes global max|w1| (172 KB, L2/LLC-cheap). Block 88: conv + fc2.
__global__ __launch_bounds__(256) void quant_all(
    const float* __restrict__ wconv, const float* __restrict__ w1,
    const float* __restrict__ w2, float* __restrict__ ws) {
  __shared__ float red[256];
  int b = blockIdx.x, t = threadIdx.x;
  if (b < 88) {
    const float4* w4 = (const float4*)w1;     // 43904/4 == 10976
    float m = 0.f;
    for (int i = t; i < 10976; i += 256) {
      float4 v = w4[i];
      m = fmaxf(m, fmaxf(fmaxf(fabsf(v.x), fabsf(v.y)),
                         fmaxf(fabsf(v.z), fabsf(v.w))));
    }
    red[t] = m;
    __syncthreads();
    for (int s = 128; s > 0; s >>= 1) {
      if (t < s) red[t] = fmaxf(red[t], red[t + s]);
      __syncthreads();
    }
    float s = red[0] * (1.0f / 7.0f);
    #pragma unroll
    for (int k = 0; k < 2; ++k) {
      int idx = b * 512 + k * 256 + t;
      if (idx < 43904) {
        float q = q4(w1[idx], s);
        int o = idx / 343;
        int j = idx - o * 343;
        ws[WS_W1T + j * 128 + o] = q;         // transpose for coalesced FC1
      }
    }
  } else {
    float mc = (t < 75) ? fabsf(wconv[t]) : 0.f;
    float m2 = 0.f;
    for (int i = t; i < 512; i += 256) m2 = fmaxf(m2, fabsf(w2[i]));
    red[t] = mc;
    __syncthreads();
    for (int s = 128; s > 0; s >>= 1) {
      if (t < s) red[t] = fmaxf(red[t], red[t + s]);
      __syncthreads();
    }
    float sc = red[0] * (1.0f / 7.0f);
    __syncthreads();
    red[t] = m2;
    __syncthreads();
    for (int s = 128; s > 0; s >>= 1) {
      if (t < s) red[t] = fmaxf(red[t], red[t + s]);
      __syncthreads();
    }
    float s2 = red[0] * (1.0f / 7.0f);
    if (t < 75) ws[WS_WCONV + t] = q4(wconv[t], sc);
    #pragma unroll
    for (int k = 0; k < 2; ++k) {
      int idx = k * 256 + t;
      ws[WS_W2 + idx] = q4(w2[idx], s2);
    }
  }
}

// Conv inner phase (R3-proven math). npf threads, pd = pd_off + t/49.
// xs holds depths [4*pd_off .. 4*pd_off+18] at local index d-4*pd_off.
__device__ __forceinline__ void conv_phase(
    const float* __restrict__ xs, const float* __restrict__ wq,
    int t, int npf, int pd_off, float bc, float* __restrict__ feat) {
  if (t >= npf) return;
  int pdl = t / 49;
  int rr  = t - pdl * 49;
  int ph  = rr / 7;
  int pw  = rr - ph * 7;
  float c[2][2][2];                           // [odp][ohp][owp]
  #pragma unroll
  for (int i = 0; i < 8; ++i) ((float*)c)[i] = 0.f;
  int base0 = pdl * 1984 + ph * 62 + pw * 4;  // 1984 = 4*496, 62 = 2*31
  #pragma unroll
  for (int dd = 0; dd < 7; ++dd) {
    int rbase = base0 + dd * 496;
    #pragma unroll
    for (int hh = 0; hh < 4; ++hh) {
      float row[7];
      #pragma unroll
      for (int wi = 0; wi < 7; ++wi) row[wi] = xs[rbase + hh * 31 + wi];
      #pragma unroll
      for (int odp = 0; odp < 2; ++odp) {
        int kd = dd - 2 * odp;
        if (kd < 0 || kd > 4) continue;       // folds at compile time
        #pragma unroll
        for (int ohp = 0; ohp < 2; ++ohp) {
          int kh = hh - ohp;
          if (kh < 0 || kh > 2) continue;     // folds at compile time
          #pragma unroll
          for (int owp = 0; owp < 2; ++owp) {
            float a = c[odp][ohp][owp];
            #pragma unroll
            for (int kw = 0; kw < 5; ++kw)
              a = fmaf(row[2 * owp + kw], wq[kd * 15 + kh * 5 + kw], a);
            c[odp][ohp][owp] = a;
          }
        }
      }
    }
  }
  float m = ((float*)c)[0];
  #pragma unroll
  for (int i = 1; i < 8; ++i) m = fmaxf(m, ((float*)c)[i]);
  feat[(pdl + pd_off) * 49 + rr] = m + bc;
}

// Fully fused: conv+pool (two depth chunks) + FC1 + FC2 + softmax.
// One block per batch. LDS 40.1 KB -> 4 blocks/CU; FC work of one block
// overlaps conv of co-resident blocks (no more 1-block/CU fc kernel).
__global__ __launch_bounds__(256, 4) void fused_net(
    const float* __restrict__ x, const float* __restrict__ bconv,
    const float* __restrict__ ws, const float* __restrict__ bfc1,
    const float* __restrict__ bfc2, float* __restrict__ out) {
  __shared__ float xs[9424];                  // 19 depths * 496
  __shared__ float feat[344];                 // +1: feat[343]=0 pads FC1 quads
  __shared__ float fc1p[128];
  __shared__ float a1[128];
  __shared__ float s2[4];
  int t = threadIdx.x;
  int b = blockIdx.x;
  const float* wq = ws + WS_WCONV;
  float bc = bconv[0];

  // P1: stage depths 0..18 (flat float4 copy, coalesced)
  {
    const float4* src = (const float4*)(x + (size_t)b * 15376);
    float4* dst = (float4*)xs;
    for (int i = t; i < 2356; i += 256) dst[i] = src[i];
    if (t == 0) feat[343] = 0.f;
  }
  __syncthreads();
  // P2: conv pd 0..3 (196 threads)
  conv_phase(xs, wq, t, 196, 0, bc, feat);
  __syncthreads();
  // P3: stage depths 16..30 (1860 float4)
  {
    const float4* src = (const float4*)(x + (size_t)b * 15376 + 16 * 496);
    float4* dst = (float4*)xs;
    for (int i = t; i < 1860; i += 256) dst[i] = src[i];
  }
  __syncthreads();
  // P4: conv pd 4..6 (147 threads)
  conv_phase(xs, wq, t, 147, 4, bc, feat);
  __syncthreads();

  // P5: FC1 (343->128). g = j-half, o = output. Features read as b128 quads
  // (43 quads each half; g=1 tail uses feat[343]=0, w1T row 343 lands in
  // finite W2 region * 0.0 -> exact). w1T loads lane-coalesced.
  int g = t >> 7, o = t & 127;
  {
    const float* w1T = ws + WS_W1T;
    int j0 = g ? 172 : 0;
    const float4* f4 = (const float4*)&feat[j0];
    const float* wp = w1T + j0 * 128 + o;
    float p0 = 0.f, p1 = 0.f, p2 = 0.f, p3 = 0.f;
    for (int q = 0; q < 43; ++q) {
      float4 ff = f4[q];
      p0 = fmaf(ff.x, wp[0],   p0);
      p1 = fmaf(ff.y, wp[128], p1);
      p2 = fmaf(ff.z, wp[256], p2);
      p3 = fmaf(ff.w, wp[384], p3);
      wp += 512;
    }
    float acc = (p0 + p1) + (p2 + p3);
    if (g) fc1p[o] = acc;
    __syncthreads();
    if (!g) a1[o] = fmaxf(acc + fc1p[o] + bfc1[o], 0.f);
  }
  __syncthreads();

  // P6: FC2 (128->4) on one wave: lane = (kk,cls), shuffle-reduce over kk.
  if (t < 64) {
    int cls = t & 3, kk = t >> 2;             // kk 0..15, 8 k's each
    const float* w2 = ws + WS_W2 + cls * 128 + kk * 8;
    const float* av = a1 + kk * 8;
    float p = 0.f;
    #pragma unroll
    for (int i = 0; i < 8; ++i) p = fmaf(av[i], w2[i], p);
    p += __shfl_down(p, 32);
    p += __shfl_down(p, 16);
    p += __shfl_down(p, 8);
    p += __shfl_down(p, 4);
    if (t < 4) s2[t] = p + bfc2[t];
  }
  __syncthreads();
  // P7: softmax + store
  if (t < 4) {
    float v0 = s2[0], v1 = s2[1], v2 = s2[2], v3 = s2[3];
    float m = fmaxf(fmaxf(v0, v1), fmaxf(v2, v3));
    float e0 = expf(v0 - m), e1 = expf(v1 - m);
    float e2 = expf(v2 - m), e3 = expf(v3 - m);
    float inv = 1.f / (e0 + e1 + e2 + e3);
    float mine = (t == 0) ? e0 : (t == 1) ? e1 : (t == 2) ? e2 : e3;
    out[b * 4 + t] = mine * inv;
  }
}

extern "C" void kernel_launch(void* const* d_in, const int* in_sizes, int n_in,
                              void* d_out, int out_size, void* d_ws, size_t ws_size,
                              hipStream_t stream) {
  const float* x     = (const float*)d_in[0];
  const float* wconv = (const float*)d_in[1];
  const float* bconv = (const float*)d_in[2];
  const float* wfc1  = (const float*)d_in[3];
  const float* bfc1  = (const float*)d_in[4];
  const float* wfc2  = (const float*)d_in[5];
  const float* bfc2  = (const float*)d_in[6];
  float* out = (float*)d_out;
  float* ws  = (float*)d_ws;

  quant_all<<<89, 256, 0, stream>>>(wconv, wfc1, wfc2, ws);
  fused_net<<<2048, 256, 0, stream>>>(x, bconv, ws, bfc1, bfc2, out);
}